// Round 1
// baseline (164.064 us; speedup 1.0000x reference)
//
#include <hip/hip_runtime.h>

// MoE gate: logits = x @ W^T  (x: [16384,2048] f32, W: [64,2048] f32)
// softmax over 64 experts, top-8 -> weights (f32) + indices (stored as f32).
// d_out layout: [16384*8 weights][16384*8 indices-as-float].
//
// Round 1: fp32 VALU tiled GEMM + fused softmax/top-k epilogue.
// Block = 64 tokens x 64 experts, BK=64, 256 threads, thread = 4x4 outputs,
// float4 partial accumulators (4 independent k-partials -> low accum error,
// protects top-k index agreement with the numpy reference on near-ties).

#define N_TOKENS 16384
#define DIM      2048
#define N_EXP    64
#define TOPK     8
#define BT       64
#define BK       64

__global__ __launch_bounds__(256) void gate_fused_kernel(
    const float* __restrict__ x, const float* __restrict__ W,
    float* __restrict__ out)
{
    // Row-major tiles with XOR slot swizzle: 16B-slot s = kv ^ (row>>2).
    // Conflict-free for float4 writes (slot = kv ^ const per wave) and for
    // compute reads (4 or 16 distinct slots per instruction).
    __shared__ float xs[BT * BK];        // 16 KB
    __shared__ float ws[N_EXP * BK];     // 16 KB
    __shared__ float lg[BT * 65];        // 16.25 KB logits, pad 65 vs conflicts

    const int tid = threadIdx.x;
    const int bt0 = blockIdx.x * BT;
    const int tx  = tid & 15;   // expert group: experts 4*tx..4*tx+3
    const int ty  = tid >> 4;   // token group:  tokens  4*ty..4*ty+3 (0..15)
    const int kv  = tid & 15;   // k-vec index for staging loads
    const int r0  = tid >> 4;   // row base for staging loads

    // ---- prefetch chunk 0 into registers ----
    float4 xr[4], wr[4];
#pragma unroll
    for (int r = 0; r < 4; ++r) {
        const int row = r0 + 16 * r;
        xr[r] = *(const float4*)(x + (size_t)(bt0 + row) * DIM + kv * 4);
        wr[r] = *(const float4*)(W + (size_t)row * DIM + kv * 4);
    }

    float4 acc[4][4];
#pragma unroll
    for (int i = 0; i < 4; ++i)
#pragma unroll
        for (int j = 0; j < 4; ++j)
            acc[i][j] = make_float4(0.f, 0.f, 0.f, 0.f);

    // ---- K loop ----
    for (int c = 0; c < DIM / BK; ++c) {
        __syncthreads();   // LDS free from previous compute
#pragma unroll
        for (int r = 0; r < 4; ++r) {
            const int row  = r0 + 16 * r;
            const int slot = (kv ^ (row >> 2)) & 15;
            *(float4*)(xs + row * BK + slot * 4) = xr[r];
            *(float4*)(ws + row * BK + slot * 4) = wr[r];
        }
        __syncthreads();

        // prefetch next chunk (loads stay in flight under compute)
        if (c + 1 < DIM / BK) {
            const int k0 = (c + 1) * BK;
#pragma unroll
            for (int r = 0; r < 4; ++r) {
                const int row = r0 + 16 * r;
                xr[r] = *(const float4*)(x + (size_t)(bt0 + row) * DIM + k0 + kv * 4);
                wr[r] = *(const float4*)(W + (size_t)row * DIM + k0 + kv * 4);
            }
        }

#pragma unroll
        for (int kc = 0; kc < 16; ++kc) {
            float4 xv[4], wv[4];
#pragma unroll
            for (int i = 0; i < 4; ++i)
                xv[i] = *(const float4*)(xs + (4 * ty + i) * BK + ((kc ^ ty) & 15) * 4);
#pragma unroll
            for (int j = 0; j < 4; ++j)
                wv[j] = *(const float4*)(ws + (4 * tx + j) * BK + ((kc ^ tx) & 15) * 4);
#pragma unroll
            for (int i = 0; i < 4; ++i)
#pragma unroll
                for (int j = 0; j < 4; ++j) {
                    acc[i][j].x += xv[i].x * wv[j].x;
                    acc[i][j].y += xv[i].y * wv[j].y;
                    acc[i][j].z += xv[i].z * wv[j].z;
                    acc[i][j].w += xv[i].w * wv[j].w;
                }
        }
    }

    // ---- reduce 4 partials pairwise, stage logits to LDS ----
#pragma unroll
    for (int i = 0; i < 4; ++i)
#pragma unroll
        for (int j = 0; j < 4; ++j) {
            const float v = (acc[i][j].x + acc[i][j].y) + (acc[i][j].z + acc[i][j].w);
            lg[(4 * ty + i) * 65 + 4 * tx + j] = v;
        }
    __syncthreads();

    // ---- fused softmax + top-8 epilogue: wave 0, one lane per token ----
    if (tid < BT) {
        const float* rowp = lg + tid * 65;

        float m = -3.402823466e38f;
        for (int e = 0; e < N_EXP; ++e) m = fmaxf(m, rowp[e]);
        float s = 0.f;
        for (int e = 0; e < N_EXP; ++e) s += expf(rowp[e] - m);

        // top-8 insertion; strict '>' => ties keep lower index first (jax.lax.top_k)
        float tv[8];
        int   ti8[8];
#pragma unroll
        for (int i = 0; i < 8; ++i) { tv[i] = -3.402823466e38f; ti8[i] = 0; }
        for (int e = 0; e < N_EXP; ++e) {
            const float v = rowp[e];
            if (v > tv[7]) {
                tv[7] = v; ti8[7] = e;
#pragma unroll
                for (int q = 7; q > 0; --q) {
                    if (tv[q] > tv[q - 1]) {
                        const float fv = tv[q]; tv[q] = tv[q - 1]; tv[q - 1] = fv;
                        const int   iv = ti8[q]; ti8[q] = ti8[q - 1]; ti8[q - 1] = iv;
                    }
                }
            }
        }

        float* ow = out + (size_t)(bt0 + tid) * TOPK;
        float* oi = out + (size_t)N_TOKENS * TOPK + (size_t)(bt0 + tid) * TOPK;
#pragma unroll
        for (int i = 0; i < 8; ++i) {
            ow[i] = expf(tv[i] - m) / s;   // ROUTE_SCALE == 1.0
            oi[i] = (float)ti8[i];
        }
    }
}

extern "C" void kernel_launch(void* const* d_in, const int* in_sizes, int n_in,
                              void* d_out, int out_size, void* d_ws, size_t ws_size,
                              hipStream_t stream) {
    const float* x = (const float*)d_in[0];
    const float* W = (const float*)d_in[1];
    float* out = (float*)d_out;
    dim3 grid(N_TOKENS / BT);
    dim3 block(256);
    hipLaunchKernelGGL(gate_fused_kernel, grid, block, 0, stream, x, W, out);
}

// Round 2
// 72.985 us; speedup vs baseline: 2.2479x; 2.2479x over previous
//
#include <hip/hip_runtime.h>

// MoE gate: logits = x @ W^T (x:[16384,2048] f32, W:[64,2048] f32),
// softmax over 64 experts, top-8 -> weights f32 + indices stored as f32.
//
// R2: MFMA bf16 3-way exact-split (6 products ~= fp32 accuracy), operands
// direct from global (x coalesced 128B segments, W L2-resident), no LDS on
// the hot path. Wave = 32 tok x 64 exp x K/4; block = 4 waves (K-split),
// LDS only for partial combine + fused softmax/top-8 epilogue.

typedef __attribute__((ext_vector_type(8))) short short8;
typedef __attribute__((ext_vector_type(4))) float f32x4;

#define NT    16384
#define DIMK  2048
#define NE    64
#define TOPKK 8
#define TT    32            // tokens per block
#define NW    4             // waves per block (K-split)
#define KSL   (DIMK / NW)   // 512 per-wave K slice
#define KST   (KSL / 32)    // 16 K-steps of 32

union U4S8 { unsigned int u[4]; short8 s; };

// Bit-exact 3-way bf16 split of 8 f32: f = H + M + L + eps, |eps| <= 2^-21|f|.
// Subtractions are exact (low-mantissa residuals are representable).
__device__ __forceinline__ void split3(const float4 a, const float4 b,
                                       short8& H, short8& M, short8& L) {
    const float f[8] = {a.x, a.y, a.z, a.w, b.x, b.y, b.z, b.w};
    U4S8 uh, um, ul;
#pragma unroll
    for (int p = 0; p < 4; ++p) {
        const float f0 = f[2 * p], f1 = f[2 * p + 1];
        const unsigned int t0 = __float_as_uint(f0) & 0xFFFF0000u;
        const unsigned int t1 = __float_as_uint(f1) & 0xFFFF0000u;
        uh.u[p] = (t0 >> 16) | t1;
        const float r0 = f0 - __uint_as_float(t0);
        const float r1 = f1 - __uint_as_float(t1);
        const unsigned int v0 = __float_as_uint(r0) & 0xFFFF0000u;
        const unsigned int v1 = __float_as_uint(r1) & 0xFFFF0000u;
        um.u[p] = (v0 >> 16) | v1;
        const float s0 = r0 - __uint_as_float(v0);
        const float s1 = r1 - __uint_as_float(v1);
        ul.u[p] = (__float_as_uint(s0) >> 16) | (__float_as_uint(s1) & 0xFFFF0000u);
    }
    H = uh.s; M = um.s; L = ul.s;
}

__device__ __forceinline__ f32x4 mfma6(short8 ah, short8 am, short8 al,
                                       short8 bh, short8 bm, short8 bl, f32x4 c) {
    c = __builtin_amdgcn_mfma_f32_16x16x32_bf16(ah, bh, c, 0, 0, 0);
    c = __builtin_amdgcn_mfma_f32_16x16x32_bf16(ah, bm, c, 0, 0, 0);
    c = __builtin_amdgcn_mfma_f32_16x16x32_bf16(am, bh, c, 0, 0, 0);
    c = __builtin_amdgcn_mfma_f32_16x16x32_bf16(ah, bl, c, 0, 0, 0);
    c = __builtin_amdgcn_mfma_f32_16x16x32_bf16(am, bm, c, 0, 0, 0);
    c = __builtin_amdgcn_mfma_f32_16x16x32_bf16(al, bh, c, 0, 0, 0);
    return c;
}

__device__ __forceinline__ void load_step(const float* xp0, const float* xp1,
                                          const float* wp, int koff,
                                          float4 xb[2][2], float4 wb[4][2]) {
#pragma unroll
    for (int h = 0; h < 2; ++h) {
        xb[0][h] = *(const float4*)(xp0 + koff + 4 * h);
        xb[1][h] = *(const float4*)(xp1 + koff + 4 * h);
    }
#pragma unroll
    for (int n = 0; n < 4; ++n)
#pragma unroll
        for (int h = 0; h < 2; ++h)
            wb[n][h] = *(const float4*)(wp + (size_t)n * 16 * DIMK + koff + 4 * h);
}

__device__ __forceinline__ void do_step(const float4 xc[2][2], const float4 wc[4][2],
                                        f32x4 acc[2][4]) {
    short8 ah[2], am[2], al[2];
#pragma unroll
    for (int m = 0; m < 2; ++m) split3(xc[m][0], xc[m][1], ah[m], am[m], al[m]);
#pragma unroll
    for (int n = 0; n < 4; ++n) {
        short8 bh, bm, bl;
        split3(wc[n][0], wc[n][1], bh, bm, bl);
#pragma unroll
        for (int m = 0; m < 2; ++m)
            acc[m][n] = mfma6(ah[m], am[m], al[m], bh, bm, bl, acc[m][n]);
    }
}

__global__ __launch_bounds__(256, 2) void gate_mfma_kernel(
    const float* __restrict__ x, const float* __restrict__ W,
    float* __restrict__ out)
{
    __shared__ float lg[NW][TT][NE + 1];   // 33.3 KB: partials + epilogue

    const int tid = threadIdx.x;
    const int w   = tid >> 6;      // wave id = K-slice id
    const int l   = tid & 63;
    const int j   = l & 15;        // A: token row in tile / B: expert col in tile
    const int g   = l >> 4;        // k-group: k = 8*g + i
    const int bt0 = blockIdx.x * TT;
    const int kb  = w * KSL;

    const float* xp0 = x + (size_t)(bt0 + j) * DIMK + kb + 8 * g;
    const float* xp1 = xp0 + (size_t)16 * DIMK;
    const float* wp  = W + (size_t)j * DIMK + kb + 8 * g;

    f32x4 acc[2][4];
#pragma unroll
    for (int m = 0; m < 2; ++m)
#pragma unroll
        for (int n = 0; n < 4; ++n)
            acc[m][n] = (f32x4){0.f, 0.f, 0.f, 0.f};

    float4 xA[2][2], wA[4][2], xB[2][2], wB[4][2];
    load_step(xp0, xp1, wp, 0, xA, wA);

#pragma unroll 1
    for (int s = 0; s < KST; s += 2) {
        load_step(xp0, xp1, wp, 32 * (s + 1), xB, wB);   // prefetch s+1
        do_step(xA, wA, acc);                            // compute s
        if (s + 2 < KST)
            load_step(xp0, xp1, wp, 32 * (s + 2), xA, wA); // prefetch s+2
        do_step(xB, wB, acc);                            // compute s+1
    }

    // ---- write partial logits; C/D layout: row=(l>>4)*4+q, col=l&15 ----
#pragma unroll
    for (int m = 0; m < 2; ++m)
#pragma unroll
        for (int n = 0; n < 4; ++n)
#pragma unroll
            for (int q = 0; q < 4; ++q)
                lg[w][16 * m + 4 * g + q][16 * n + j] = acc[m][n][q];
    __syncthreads();

    // ---- deterministic K-split reduction: 2048 values / 256 threads ----
#pragma unroll
    for (int r = 0; r < (TT * NE) / 256; ++r) {
        const int idx = tid + r * 256;
        const int t = idx >> 6, e = idx & 63;
        lg[0][t][e] += lg[1][t][e] + lg[2][t][e] + lg[3][t][e];
    }
    __syncthreads();

    // ---- fused softmax + top-8: one lane per token ----
    if (tid < TT) {
        const float* rowp = &lg[0][tid][0];

        float mx = -3.402823466e38f;
        for (int e = 0; e < NE; ++e) mx = fmaxf(mx, rowp[e]);
        float sden = 0.f;
        for (int e = 0; e < NE; ++e) sden += expf(rowp[e] - mx);

        float tv[TOPKK];
        int   ti[TOPKK];
#pragma unroll
        for (int i = 0; i < TOPKK; ++i) { tv[i] = -3.402823466e38f; ti[i] = 0; }
        for (int e = 0; e < NE; ++e) {
            const float v = rowp[e];
            if (v > tv[TOPKK - 1]) {
                tv[TOPKK - 1] = v; ti[TOPKK - 1] = e;
#pragma unroll
                for (int q = TOPKK - 1; q > 0; --q) {
                    if (tv[q] > tv[q - 1]) {
                        const float fv = tv[q]; tv[q] = tv[q - 1]; tv[q - 1] = fv;
                        const int   iv = ti[q]; ti[q] = ti[q - 1]; ti[q - 1] = iv;
                    }
                }
            }
        }

        float* ow = out + (size_t)(bt0 + tid) * TOPKK;
        float* oi = out + (size_t)NT * TOPKK + (size_t)(bt0 + tid) * TOPKK;
#pragma unroll
        for (int i = 0; i < TOPKK; ++i) {
            ow[i] = expf(tv[i] - mx) / sden;   // ROUTE_SCALE == 1.0
            oi[i] = (float)ti[i];
        }
    }
}

extern "C" void kernel_launch(void* const* d_in, const int* in_sizes, int n_in,
                              void* d_out, int out_size, void* d_ws, size_t ws_size,
                              hipStream_t stream) {
    const float* x = (const float*)d_in[0];
    const float* W = (const float*)d_in[1];
    float* out = (float*)d_out;
    dim3 grid(NT / TT);   // 512
    dim3 block(256);
    hipLaunchKernelGGL(gate_mfma_kernel, grid, block, 0, stream, x, W, out);
}